// Round 3
// baseline (279653.540 us; speedup 1.0000x reference)
//
#include <hip/hip_runtime.h>

// RNNDetector: 2-layer LSTM (H=64), T=262144 sequential steps + 16-wide head.
// 1 workgroup, 1024 threads (16 waves, 4 waves/SIMD -> VGPR cap 128).
// Round-2 lesson: VGPR_Count=84 proved 128-float/thread weight arrays get
// spilled; this round shards rows across LANE PAIRS so no thread holds more
// than 64 weight floats (16 v4) -> ~105 VGPR peak, under the 128 cap.
//   threads   0-511 : layer 0.  lane l: e=l>>3, r=(l>>1)&3 (gate), half=l&1.
//                     holds Whh0[r*64+e][half*32 .. +32) = 8 v4.
//   threads 512-1023: layer 1.  same (e,r,half); half picks Wih1 vs Whh1 row
//                     (full 64 floats = 16 v4); pair dots vs h0 / h1.
// Pair partials combine via __shfl_xor(1); gates exchange via xor(2)/xor(4);
// c lives in r<2 lanes, h computed in r>=2 lanes. ONE barrier per superstep.
// Pipeline: step s computes h0(s), h1(s-1), out(s-2). h double-buffered in LDS.

constexpr int T = 262144;

typedef float v4 __attribute__((ext_vector_type(4)));

__device__ __forceinline__ float rcp_f(float x) { return __builtin_amdgcn_rcpf(x); }

#define DECL_LOAD8(V, ptr)                                                     \
  const v4* V##_p = (const v4*)(ptr);                                          \
  v4 V##0=V##_p[0], V##1=V##_p[1], V##2=V##_p[2], V##3=V##_p[3],               \
     V##4=V##_p[4], V##5=V##_p[5], V##6=V##_p[6], V##7=V##_p[7]

#define DECL_LOAD16(V, ptr)                                                    \
  DECL_LOAD8(V, ptr);                                                          \
  v4 V##8=V##_p[8],  V##9=V##_p[9],  V##10=V##_p[10], V##11=V##_p[11],         \
     V##12=V##_p[12], V##13=V##_p[13], V##14=V##_p[14], V##15=V##_p[15]

#define DOT8(res, V, hp) {                                                     \
  v4 _x = V##0*(hp)[0]; v4 _y = V##1*(hp)[1];                                  \
  _x += V##2*(hp)[2]; _y += V##3*(hp)[3];                                      \
  _x += V##4*(hp)[4]; _y += V##5*(hp)[5];                                      \
  _x += V##6*(hp)[6]; _y += V##7*(hp)[7];                                      \
  v4 _s = _x + _y; res = (_s.x+_s.y)+(_s.z+_s.w); }

#define DOT16(res, V, hp) {                                                    \
  v4 _x = V##0*(hp)[0];  v4 _y = V##1*(hp)[1];                                 \
  _x += V##2*(hp)[2];   _y += V##3*(hp)[3];                                    \
  _x += V##4*(hp)[4];   _y += V##5*(hp)[5];                                    \
  _x += V##6*(hp)[6];   _y += V##7*(hp)[7];                                    \
  _x += V##8*(hp)[8];   _y += V##9*(hp)[9];                                    \
  _x += V##10*(hp)[10]; _y += V##11*(hp)[11];                                  \
  _x += V##12*(hp)[12]; _y += V##13*(hp)[13];                                  \
  _x += V##14*(hp)[14]; _y += V##15*(hp)[15];                                  \
  v4 _s = _x + _y; res = (_s.x+_s.y)+(_s.z+_s.w); }

// Shared gate/state path. pre holds this lane's gate pre-activation (both
// lanes of a pair hold the same value). c is live in r<2 lanes only.
// Returns h (valid in r>=2 lanes).
__device__ __forceinline__ float gate_update(float pre, int r, float& c) {
  const bool isG = (r == 2);
  float z  = fminf(fmaxf(pre * (isG ? 2.f : 1.f), -30.f), 30.f);
  float ex = __expf(-z);
  float a  = (isG ? (1.f - ex) : 1.f) * rcp_f(1.f + ex);
  float b  = __shfl_xor(a, 2);          // partner gate within (i,f) / (g,o)
  float iv = (r == 0) ? a : b;          // valid in r<2
  float fv = (r == 1) ? a : b;
  float gv = (r == 2) ? a : b;          // valid in r>=2
  float ov = (r == 3) ? a : b;
  float s1 = (r < 2) ? iv : gv;
  float rc = __shfl_xor(s1, 4);         // r<2 lanes receive g; r>=2 receive i
  float cn = fmaf(fv, c, iv * rc);      // c_new (meaningful in r<2 lanes)
  float cx = __shfl_xor(cn, 4);         // ship c_new to r>=2 lanes
  if (r < 2) c = cn;
  float cc = (r < 2) ? cn : cx;
  float zz = fminf(fmaxf(cc, -15.f), 15.f);
  float e2 = __expf(-2.f * zz);
  float th = (1.f - e2) * rcp_f(1.f + e2);
  return ov * th;                        // h (valid in r>=2 lanes)
}

__global__ __launch_bounds__(1024, 4) void rnn_fused(
    const float* __restrict__ y,
    const float* __restrict__ Wih0, const float* __restrict__ Whh0,
    const float* __restrict__ bih0, const float* __restrict__ bhh0,
    const float* __restrict__ Wih1, const float* __restrict__ Whh1,
    const float* __restrict__ bih1, const float* __restrict__ bhh1,
    const float* __restrict__ Wlin, const float* __restrict__ blin,
    float* __restrict__ out)
{
  const int tid  = threadIdx.x;
  const bool isL1 = tid >= 512;
  const int l    = tid & 511;
  const int e    = l >> 3;
  const int r    = (l >> 1) & 3;
  const int half = l & 1;
  const int j    = r * 64 + e;          // weight row, PyTorch gate order

  __shared__ __align__(16) float h0b[2][64];
  __shared__ __align__(16) float h1b[2][64];

  if (tid < 64) { h0b[0][tid] = 0.f; h0b[1][tid] = 0.f;
                  h1b[0][tid] = 0.f; h1b[1][tid] = 0.f; }
  __syncthreads();

  if (!isL1) {
    // ================= layer 0 (+ head on tid<256) =================
    DECL_LOAD8(A, Whh0 + j * 64 + half * 32);
    const float bb  = bih0[j] + bhh0[j];
    const float wi0 = Wih0[j];
    const int  hm = tid >> 4;            // head: output idx (tid<256)
    const int  hk = tid & 15;            // head: v4 slice of h1
    v4 WL = {0.f,0.f,0.f,0.f};
    float bl = 0.f;
    if (tid < 256) {
      WL = *((const v4*)(Wlin + hm * 64) + hk);
      if ((tid & 15) == 0) bl = blin[hm];
    }
    float c = 0.f;
    float y_cur = y[0];

    #pragma unroll 1
    for (int s = 0; s < T + 2; ++s) {
      const int cur = s & 1;
      // ---- head: out(s-2) from h1(s-2) = h1b[cur] ----
      if (tid < 256 && s >= 2) {
        v4 hh = *((const v4*)h1b[cur] + hk);
        v4 tt = WL * hh;
        float p = (tt.x + tt.y) + (tt.z + tt.w);
        p += __shfl_xor(p, 1);
        p += __shfl_xor(p, 2);
        p += __shfl_xor(p, 4);
        p += __shfl_xor(p, 8);
        if ((tid & 15) == 0) out[(s - 2) * 16 + hm] = p + bl;
      }
      // ---- layer 0: h0(s) from h0(s-1) = h0b[cur], y[s] ----
      if (s < T) {
        float y_nxt = (s + 1 < T) ? y[s + 1] : 0.f;   // prefetch
        const v4* hp = (const v4*)h0b[cur] + (half << 3);
        float d; DOT8(d, A, hp);
        d += __shfl_xor(d, 1);                         // combine half-rows
        float pre = d + fmaf(y_cur, wi0, bb);
        float h = gate_update(pre, r, c);
        if ((l & 7) == 7) h0b[cur ^ 1][e] = h;         // lane r=3,half=1
        y_cur = y_nxt;
      }
      __syncthreads();
    }
  } else {
    // ================= layer 1 =================
    const float* wsrc = (half ? Whh1 : Wih1) + j * 64;
    DECL_LOAD16(W, wsrc);
    const float bb = bih1[j] + bhh1[j];
    // half=0 dots vs h0 (x_t), half=1 dots vs h1 (recurrent)
    const v4* hpb0 = (const v4*)(half ? h1b[0] : h0b[0]);
    const v4* hpb1 = (const v4*)(half ? h1b[1] : h0b[1]);
    float c = 0.f;

    #pragma unroll 1
    for (int s = 0; s < T + 2; ++s) {
      // ---- layer 1: h1(s-1) from h0(s-1), h1(s-2) (both in buf s&1) ----
      if (s >= 1 && s <= T) {
        const v4* hp = (s & 1) ? hpb1 : hpb0;
        float d; DOT16(d, W, hp);
        d += __shfl_xor(d, 1);                         // Wih1·h0 + Whh1·h1
        float pre = d + bb;
        float h = gate_update(pre, r, c);
        if ((l & 7) == 7) h1b[(s & 1) ^ 1][e] = h;
      }
      __syncthreads();
    }
  }
}

extern "C" void kernel_launch(void* const* d_in, const int* in_sizes, int n_in,
                              void* d_out, int out_size, void* d_ws, size_t ws_size,
                              hipStream_t stream) {
  const float* y    = (const float*)d_in[0];
  const float* Wih0 = (const float*)d_in[1];
  const float* Whh0 = (const float*)d_in[2];
  const float* bih0 = (const float*)d_in[3];
  const float* bhh0 = (const float*)d_in[4];
  const float* Wih1 = (const float*)d_in[5];
  const float* Whh1 = (const float*)d_in[6];
  const float* bih1 = (const float*)d_in[7];
  const float* bhh1 = (const float*)d_in[8];
  const float* Wlin = (const float*)d_in[9];
  const float* blin = (const float*)d_in[10];

  rnn_fused<<<dim3(1), dim3(1024), 0, stream>>>(
      y, Wih0, Whh0, bih0, bhh0, Wih1, Whh1, bih1, bhh1, Wlin, blin,
      (float*)d_out);
}

// Round 4
// 238784.912 us; speedup vs baseline: 1.1712x; 1.1712x over previous
//
#include <hip/hip_runtime.h>

// RNNDetector: 2-layer LSTM (H=64), T=262144 sequential steps + 16-wide head.
// 1 workgroup, 1024 threads (16 waves). Round-3 lesson: VGPR_Count=48 proved
// the allocator REMATERIALIZES loop-invariant weight loads (re-reads L1/L2
// every step, ~2500 cyc/step). Fix: pin weight registers with opaque inline
// asm so their defs are not rematerializable. Also: 16-float LDS skew kills
// the 512-conflict-cycles/step bank aliasing (paired reads were 128B/512B
// apart = same banks); y prefetch queue depth 4 hides HBM-miss latency.
//   threads   0-511 : layer 0.  lane l: e=l>>3, r=(l>>1)&3 (gate), half=l&1.
//                     holds Whh0[r*64+e][half*32 .. +32) = 8 v4 (pinned).
//                     tid<256 also computes the 16-wide linear head.
//   threads 512-1023: layer 1.  same (e,r,half); half picks Wih1 vs Whh1 row
//                     (16 v4, pinned); pair dots vs h0 / h1, combine xor(1).
// Gates exchange via DPP shuffles xor(2)/xor(4); c lives in r<2 lanes.
// ONE barrier per superstep; h double-buffered. Step s: h0(s), h1(s-1), out(s-2).

constexpr int T = 262144;

typedef float v4 __attribute__((ext_vector_type(4)));

__device__ __forceinline__ float rcp_f(float x) { return __builtin_amdgcn_rcpf(x); }

#define PIN(x) asm volatile("" : "+v"(x))

#define DECL_LOAD8(V, ptr)                                                     \
  const v4* V##_p = (const v4*)(ptr);                                          \
  v4 V##0=V##_p[0], V##1=V##_p[1], V##2=V##_p[2], V##3=V##_p[3],               \
     V##4=V##_p[4], V##5=V##_p[5], V##6=V##_p[6], V##7=V##_p[7]

#define DECL_LOAD16(V, ptr)                                                    \
  DECL_LOAD8(V, ptr);                                                          \
  v4 V##8=V##_p[8],  V##9=V##_p[9],  V##10=V##_p[10], V##11=V##_p[11],         \
     V##12=V##_p[12], V##13=V##_p[13], V##14=V##_p[14], V##15=V##_p[15]

#define PIN8(V)  { PIN(V##0); PIN(V##1); PIN(V##2); PIN(V##3);                 \
                   PIN(V##4); PIN(V##5); PIN(V##6); PIN(V##7); }
#define PIN16(V) { PIN8(V); PIN(V##8);  PIN(V##9);  PIN(V##10); PIN(V##11);    \
                   PIN(V##12); PIN(V##13); PIN(V##14); PIN(V##15); }

#define DOT8(res, V, hp) {                                                     \
  v4 _x = V##0*(hp)[0]; v4 _y = V##1*(hp)[1];                                  \
  _x += V##2*(hp)[2]; _y += V##3*(hp)[3];                                      \
  _x += V##4*(hp)[4]; _y += V##5*(hp)[5];                                      \
  _x += V##6*(hp)[6]; _y += V##7*(hp)[7];                                      \
  v4 _s = _x + _y; res = (_s.x+_s.y)+(_s.z+_s.w); }

#define DOT16(res, V, hp) {                                                    \
  v4 _x = V##0*(hp)[0];  v4 _y = V##1*(hp)[1];                                 \
  _x += V##2*(hp)[2];   _y += V##3*(hp)[3];                                    \
  _x += V##4*(hp)[4];   _y += V##5*(hp)[5];                                    \
  _x += V##6*(hp)[6];   _y += V##7*(hp)[7];                                    \
  _x += V##8*(hp)[8];   _y += V##9*(hp)[9];                                    \
  _x += V##10*(hp)[10]; _y += V##11*(hp)[11];                                  \
  _x += V##12*(hp)[12]; _y += V##13*(hp)[13];                                  \
  _x += V##14*(hp)[14]; _y += V##15*(hp)[15];                                  \
  v4 _s = _x + _y; res = (_s.x+_s.y)+(_s.z+_s.w); }

// pre: this lane's gate pre-activation (both lanes of a pair identical).
// c lives in r<2 lanes. Returns h (valid in r>=2 lanes). Shuffles are DPP.
__device__ __forceinline__ float gate_update(float pre, int r, float& c) {
  const bool isG = (r == 2);
  float z  = fminf(fmaxf(pre * (isG ? 2.f : 1.f), -30.f), 30.f);
  float ex = __expf(-z);
  float a  = (isG ? (1.f - ex) : 1.f) * rcp_f(1.f + ex);
  float b  = __shfl_xor(a, 2);          // partner gate within (i,f) / (g,o)
  float iv = (r == 0) ? a : b;
  float fv = (r == 1) ? a : b;
  float gv = (r == 2) ? a : b;
  float ov = (r == 3) ? a : b;
  float s1 = (r < 2) ? iv : gv;
  float rc = __shfl_xor(s1, 4);         // r<2 get g; r>=2 get i
  float cn = fmaf(fv, c, iv * rc);      // c_new (valid in r<2)
  float cx = __shfl_xor(cn, 4);
  if (r < 2) c = cn;
  float cc = (r < 2) ? cn : cx;
  float zz = fminf(fmaxf(cc, -15.f), 15.f);
  float e2 = __expf(-2.f * zz);
  float th = (1.f - e2) * rcp_f(1.f + e2);
  return ov * th;                        // h (valid in r>=2)
}

__global__ __launch_bounds__(1024, 4) void rnn_fused(
    const float* __restrict__ y,
    const float* __restrict__ Wih0, const float* __restrict__ Whh0,
    const float* __restrict__ bih0, const float* __restrict__ bhh0,
    const float* __restrict__ Wih1, const float* __restrict__ Whh1,
    const float* __restrict__ bih1, const float* __restrict__ bhh1,
    const float* __restrict__ Wlin, const float* __restrict__ blin,
    float* __restrict__ out)
{
  const int tid  = threadIdx.x;
  const bool isL1 = tid >= 512;
  const int l    = tid & 511;
  const int e    = l >> 3;
  const int r    = (l >> 1) & 3;
  const int half = l & 1;
  const int j    = r * 64 + e;          // weight row, PyTorch gate order

  // LDS skew layout (floats): h0A@0 (bank0), h0B@144 (bank16), h1@272 (bank16)
  __shared__ __align__(16) float smem[400];
  float* const h0A = smem;              // [2][64] copy read by half=0 lanes
  float* const h0B = smem + 144;        // [2][64] copy read by half=1 lanes
  float* const h1s = smem + 272;        // [2][64]

  if (tid < 400) smem[tid] = 0.f;
  __syncthreads();

  if (!isL1) {
    // ================= layer 0 (+ head on tid<256) =================
    DECL_LOAD8(A, Whh0 + j * 64 + half * 32);
    PIN8(A);
    float bb  = bih0[j] + bhh0[j];
    float wi0 = Wih0[j];
    PIN(bb); PIN(wi0);
    const int hm = tid >> 4;             // head: output idx (tid<256)
    const int hk = tid & 15;             // head: v4 slice of h1
    v4 WL = {0.f,0.f,0.f,0.f};
    float bl = 0.f;
    if (tid < 256) {
      WL = *((const v4*)(Wlin + hm * 64) + hk);
      if ((tid & 15) == 0) bl = blin[hm];
    }
    PIN(WL); PIN(bl);
    float c = 0.f;
    float yq0 = y[0], yq1 = y[1], yq2 = y[2], yq3 = y[3];  // prefetch queue

    #pragma unroll 1
    for (int s = 0; s < T + 2; ++s) {
      const int cur = s & 1;
      // ---- head: out(s-2) from h1(s-2) = h1s[cur] ----
      if (tid < 256 && s >= 2) {
        v4 hh = *((const v4*)(h1s + cur * 64) + hk);
        v4 tt = WL * hh;
        float p = (tt.x + tt.y) + (tt.z + tt.w);
        p += __shfl_xor(p, 1);
        p += __shfl_xor(p, 2);
        p += __shfl_xor(p, 4);
        p += __shfl_xor(p, 8);
        if ((tid & 15) == 0) out[(s - 2) * 16 + hm] = p + bl;
      }
      // ---- layer 0: h0(s) from h0(s-1), y[s] ----
      if (s < T) {
        // half=0 reads elements 0..31 of copy A; half=1 reads 32..63 of copy B
        const v4* hp = (const v4*)(half ? (h0B + cur * 64 + 32)
                                        : (h0A + cur * 64));
        float d; DOT8(d, A, hp);
        d += __shfl_xor(d, 1);                         // combine half-rows
        float pre = d + fmaf(yq0, wi0, bb);
        float h = gate_update(pre, r, c);
        if ((l & 7) == 6) h0A[(cur ^ 1) * 64 + e] = h; // r=3, half=0
        if ((l & 7) == 7) h0B[(cur ^ 1) * 64 + e] = h; // r=3, half=1
        yq0 = yq1; yq1 = yq2; yq2 = yq3;               // rotate prefetch queue
        yq3 = (s + 4 < T) ? y[s + 4] : 0.f;
      }
      __syncthreads();
    }
  } else {
    // ================= layer 1 =================
    DECL_LOAD16(W, (half ? Whh1 : Wih1) + j * 64);
    PIN16(W);
    float bb = bih1[j] + bhh1[j];
    PIN(bb);
    float c = 0.f;

    #pragma unroll 1
    for (int s = 0; s < T + 2; ++s) {
      // ---- layer 1: h1(s-1) from h0(s-1), h1(s-2) (both in buf s&1) ----
      if (s >= 1 && s <= T) {
        const int cur = s & 1;
        const v4* hp = (const v4*)(half ? (h1s + cur * 64)
                                        : (h0A + cur * 64));
        float d; DOT16(d, W, hp);
        d += __shfl_xor(d, 1);                         // Wih1·h0 + Whh1·h1
        float pre = d + bb;
        float h = gate_update(pre, r, c);
        if ((l & 7) == 7) h1s[(cur ^ 1) * 64 + e] = h;
      }
      __syncthreads();
    }
  }
}

extern "C" void kernel_launch(void* const* d_in, const int* in_sizes, int n_in,
                              void* d_out, int out_size, void* d_ws, size_t ws_size,
                              hipStream_t stream) {
  const float* y    = (const float*)d_in[0];
  const float* Wih0 = (const float*)d_in[1];
  const float* Whh0 = (const float*)d_in[2];
  const float* bih0 = (const float*)d_in[3];
  const float* bhh0 = (const float*)d_in[4];
  const float* Wih1 = (const float*)d_in[5];
  const float* Whh1 = (const float*)d_in[6];
  const float* bih1 = (const float*)d_in[7];
  const float* bhh1 = (const float*)d_in[8];
  const float* Wlin = (const float*)d_in[9];
  const float* blin = (const float*)d_in[10];

  rnn_fused<<<dim3(1), dim3(1024), 0, stream>>>(
      y, Wih0, Whh0, bih0, bhh0, Wih1, Whh1, bih1, bhh1, Wlin, blin,
      (float*)d_out);
}

// Round 5
// 200078.735 us; speedup vs baseline: 1.3977x; 1.1935x over previous
//
#include <hip/hip_runtime.h>

// RNNDetector: 2-layer LSTM (H=64), T=262144 sequential steps + 16-wide head.
// ROUNDS 1-4 LESSON (counter-verified): the kernel was LDS-return-BW bound —
// 192 broadcast ds_read_b128/step x ~10cyc = ~2000 cyc/step, because every
// lane read ALL 64 h values (64x replication through the 128B/cyc LDS pipe).
// FIX: K-shard each dot across 4 lanes. Lane (q,r,g): q=k-shard(2b),
// r=gate(2b), g=element-group(4b); owns 4 rows (elements 4g..4g+3, gate r)
// x 16-col chunk (L0) / 32-col chunk of [Wih1|Whh1] (L1), stored COLUMN-major
// (16/32 v4s) so a v4 accumulator carries 4 row-sums (no horizontal adds).
// h-chunk reads: 4 b128 (L0) / 8 b128 (L1) per lane -> 48 b128/step total
// (4x less LDS). Shard-reduce xor(1),xor(2); round-2-validated gate exchange
// at distances xor(8),xor(4). Weights pinned IN-LOOP (defeats remat+spill).
// 512 thr = 8 waves, LB(512,2) -> 256 VGPR budget. One barrier/superstep.
// Pipeline: step s computes h0(s), h1(s-1), out(s-2); h double-buffered.

constexpr int T = 262144;

typedef float v4 __attribute__((ext_vector_type(4)));

__device__ __forceinline__ float rcp_f(float x) { return __builtin_amdgcn_rcpf(x); }

#define PIN(x) asm volatile("" : "+v"(x))

// column j of a 4-row block: {M[r0][c], M[r0+1][c], M[r0+2][c], M[r0+3][c]}
#define LCOL(name, M, r0, c)                                                   \
  v4 name = { (M)[(r0)*64+(c)], (M)[((r0)+1)*64+(c)],                          \
              (M)[((r0)+2)*64+(c)], (M)[((r0)+3)*64+(c)] }

// acc[row] += block_cols * h_scalars  (4 cols per group, h from one v4)
#define FMAG(acc, Ca, Cb, Cc, Cd, H)                                           \
  { acc += Ca*(H).x; acc += Cb*(H).y; acc += Cc*(H).z; acc += Cd*(H).w; }

#define RED4(acc, d) { acc.x += __shfl_xor(acc.x, d);                          \
                       acc.y += __shfl_xor(acc.y, d);                          \
                       acc.z += __shfl_xor(acc.z, d);                          \
                       acc.w += __shfl_xor(acc.w, d); }

// round-2-validated gate algebra, shuffle distances 8 (r^2) and 4 (r^1).
// pre: this lane's gate-r pre-activation for element e. c kept in ALL lanes.
// Returns h (valid where r==3).
__device__ __forceinline__ float gate_update(float pre, int r, float& c) {
  const bool isG = (r == 2);
  float z  = fminf(fmaxf(pre * (isG ? 2.f : 1.f), -30.f), 30.f);
  float ex = __expf(-z);
  float a  = (isG ? (1.f - ex) : 1.f) * rcp_f(1.f + ex);
  float b2 = __shfl_xor(a, 8);          // partner gate r^2
  // r=0: a=i,b2=g | r=1: a=f,b2=o | r=2: a=g,b2=i | r=3: a=o,b2=f
  float fo = (r & 2) ? b2 : a;
  float m1 = (r & 1) ? fo : a;          // r0:i r1:f r2:g r3:f
  float m2 = (r & 1) ? c  : b2;         // r0:g r1:c r2:i r3:c
  float p  = m1 * m2;
  float cn = p + __shfl_xor(p, 4);      // i*g + f*c in all 4 lanes
  c = cn;
  float zz = fminf(fmaxf(cn, -15.f), 15.f);
  float e2 = __expf(-2.f * zz);
  float th = (1.f - e2) * rcp_f(1.f + e2);
  float oo = (r & 2) ? a : b2;          // r==3 holds o
  return oo * th;
}

__global__ __launch_bounds__(512, 2) void rnn_fused(
    const float* __restrict__ y,
    const float* __restrict__ Wih0, const float* __restrict__ Whh0,
    const float* __restrict__ bih0, const float* __restrict__ bhh0,
    const float* __restrict__ Wih1, const float* __restrict__ Whh1,
    const float* __restrict__ bih1, const float* __restrict__ bhh1,
    const float* __restrict__ Wlin, const float* __restrict__ blin,
    float* __restrict__ out)
{
  const int tid  = threadIdx.x;
  const bool isL1 = tid >= 256;
  const int l  = tid & 255;
  const int q  = l & 3;                 // k-shard
  const int r  = (l >> 2) & 3;          // gate 0=i 1=f 2=g 3=o
  const int g  = l >> 4;                // element group 0..15
  const int e  = 4 * g + q;             // this lane's element
  const int jrow = r * 64 + e;          // row for bias lookup
  const int r0 = r * 64 + 4 * g;        // first of the 4 owned rows

  // LDS: h0[2][64] @0, gap, h1[2][64] @136 (8-float skew: disjoint banks)
  __shared__ __align__(16) float smem[272];
  if (tid < 272) smem[tid] = 0.f;
  __syncthreads();

  if (!isL1) {
    // ===== layer 0 (+ head) =====
    const int c0 = 16 * q;
    LCOL(A0, Whh0, r0, c0+0);  LCOL(A1, Whh0, r0, c0+1);
    LCOL(A2, Whh0, r0, c0+2);  LCOL(A3, Whh0, r0, c0+3);
    LCOL(A4, Whh0, r0, c0+4);  LCOL(A5, Whh0, r0, c0+5);
    LCOL(A6, Whh0, r0, c0+6);  LCOL(A7, Whh0, r0, c0+7);
    LCOL(A8, Whh0, r0, c0+8);  LCOL(A9, Whh0, r0, c0+9);
    LCOL(A10, Whh0, r0, c0+10); LCOL(A11, Whh0, r0, c0+11);
    LCOL(A12, Whh0, r0, c0+12); LCOL(A13, Whh0, r0, c0+13);
    LCOL(A14, Whh0, r0, c0+14); LCOL(A15, Whh0, r0, c0+15);
    float bb  = bih0[jrow] + bhh0[jrow];
    float wi0 = Wih0[jrow];
    // head: m = tid>>4, k4 = tid&15 (reuses round-4 pattern, 0 conflicts)
    const int hm = tid >> 4, hk = tid & 15;
    v4 WL = *((const v4*)(Wlin + hm * 64) + hk);
    float bl = (hk == 0) ? blin[hm] : 0.f;
    const float* hbase = smem + c0;               // h0 chunk base
    const float* hhead = smem + 136 + 4 * hk;     // head h1 slice
    float c = 0.f;
    float yq0 = y[0], yq1 = y[1], yq2 = y[2], yq3 = y[3];

    #pragma unroll 1
    for (int s = 0; s < T + 2; ++s) {
      const int cur = s & 1, nxt = cur ^ 1;
      PIN(A0); PIN(A1); PIN(A2); PIN(A3); PIN(A4); PIN(A5); PIN(A6); PIN(A7);
      PIN(A8); PIN(A9); PIN(A10); PIN(A11); PIN(A12); PIN(A13); PIN(A14); PIN(A15);
      // ---- head: out(s-2) from h1[cur] ----
      if (s >= 2) {
        v4 hh = *(const v4*)(hhead + cur * 64);
        v4 tt = WL * hh;
        float p2 = (tt.x + tt.y) + (tt.z + tt.w);
        p2 += __shfl_xor(p2, 1);
        p2 += __shfl_xor(p2, 2);
        p2 += __shfl_xor(p2, 4);
        p2 += __shfl_xor(p2, 8);
        if (hk == 0) out[(s - 2) * 16 + hm] = p2 + bl;
      }
      // ---- layer 0: h0(s) from h0[cur], y[s] ----
      if (s < T) {
        float y_nxt = (s + 4 < T) ? y[s + 4] : 0.f;
        const v4* hp = (const v4*)(hbase + cur * 64);
        v4 H0 = hp[0], H1 = hp[1], H2 = hp[2], H3 = hp[3];
        v4 acc = {0.f,0.f,0.f,0.f}, ac2 = {0.f,0.f,0.f,0.f};
        FMAG(acc, A0, A1, A2, A3, H0);
        FMAG(ac2, A4, A5, A6, A7, H1);
        FMAG(acc, A8, A9, A10, A11, H2);
        FMAG(ac2, A12, A13, A14, A15, H3);
        acc += ac2;
        RED4(acc, 1); RED4(acc, 2);                // sum shards q
        float s1 = (q & 1) ? acc.y : acc.x;
        float s2 = (q & 1) ? acc.w : acc.z;
        float pre = ((q & 2) ? s2 : s1) + fmaf(yq0, wi0, bb);
        float h = gate_update(pre, r, c);
        if (r == 3) smem[nxt * 64 + e] = h;
        yq0 = yq1; yq1 = yq2; yq2 = yq3; yq3 = y_nxt;
      }
      __syncthreads();
    }
  } else {
    // ===== layer 1 =====
    // chunk q of [Wih1 | Whh1] columns: q<2 -> Wih1, q>=2 -> Whh1
    const float* M = (q < 2) ? Wih1 : Whh1;
    const int c0 = 32 * (q & 1);
    LCOL(B0, M, r0, c0+0);   LCOL(B1, M, r0, c0+1);
    LCOL(B2, M, r0, c0+2);   LCOL(B3, M, r0, c0+3);
    LCOL(B4, M, r0, c0+4);   LCOL(B5, M, r0, c0+5);
    LCOL(B6, M, r0, c0+6);   LCOL(B7, M, r0, c0+7);
    LCOL(B8, M, r0, c0+8);   LCOL(B9, M, r0, c0+9);
    LCOL(B10, M, r0, c0+10); LCOL(B11, M, r0, c0+11);
    LCOL(B12, M, r0, c0+12); LCOL(B13, M, r0, c0+13);
    LCOL(B14, M, r0, c0+14); LCOL(B15, M, r0, c0+15);
    LCOL(B16, M, r0, c0+16); LCOL(B17, M, r0, c0+17);
    LCOL(B18, M, r0, c0+18); LCOL(B19, M, r0, c0+19);
    LCOL(B20, M, r0, c0+20); LCOL(B21, M, r0, c0+21);
    LCOL(B22, M, r0, c0+22); LCOL(B23, M, r0, c0+23);
    LCOL(B24, M, r0, c0+24); LCOL(B25, M, r0, c0+25);
    LCOL(B26, M, r0, c0+26); LCOL(B27, M, r0, c0+27);
    LCOL(B28, M, r0, c0+28); LCOL(B29, M, r0, c0+29);
    LCOL(B30, M, r0, c0+30); LCOL(B31, M, r0, c0+31);
    float bb = bih1[jrow] + bhh1[jrow];
    // h operand chunk: q=0: h0[0:32), q=1: h0[32:64), q=2: h1[0:32), q=3: h1[32:64)
    const float* hbase = ((q < 2) ? smem : smem + 136) + 32 * (q & 1);
    float c = 0.f;

    #pragma unroll 1
    for (int s = 0; s < T + 2; ++s) {
      const int cur = s & 1, nxt = cur ^ 1;
      PIN(B0); PIN(B1); PIN(B2); PIN(B3); PIN(B4); PIN(B5); PIN(B6); PIN(B7);
      PIN(B8); PIN(B9); PIN(B10); PIN(B11); PIN(B12); PIN(B13); PIN(B14); PIN(B15);
      PIN(B16); PIN(B17); PIN(B18); PIN(B19); PIN(B20); PIN(B21); PIN(B22); PIN(B23);
      PIN(B24); PIN(B25); PIN(B26); PIN(B27); PIN(B28); PIN(B29); PIN(B30); PIN(B31);
      // ---- layer 1: h1(s-1) from h0[cur]=h0(s-1), h1[cur]=h1(s-2) ----
      if (s >= 1 && s <= T) {
        const v4* hp = (const v4*)(hbase + cur * 64);
        v4 H0 = hp[0], H1 = hp[1], H2 = hp[2], H3 = hp[3];
        v4 H4 = hp[4], H5 = hp[5], H6 = hp[6], H7 = hp[7];
        v4 acc = {0.f,0.f,0.f,0.f}, ac2 = {0.f,0.f,0.f,0.f};
        FMAG(acc, B0,  B1,  B2,  B3,  H0);
        FMAG(ac2, B4,  B5,  B6,  B7,  H1);
        FMAG(acc, B8,  B9,  B10, B11, H2);
        FMAG(ac2, B12, B13, B14, B15, H3);
        FMAG(acc, B16, B17, B18, B19, H4);
        FMAG(ac2, B20, B21, B22, B23, H5);
        FMAG(acc, B24, B25, B26, B27, H6);
        FMAG(ac2, B28, B29, B30, B31, H7);
        acc += ac2;
        RED4(acc, 1); RED4(acc, 2);                // sum 4 shards = full 128-K
        float s1 = (q & 1) ? acc.y : acc.x;
        float s2 = (q & 1) ? acc.w : acc.z;
        float pre = ((q & 2) ? s2 : s1) + bb;
        float h = gate_update(pre, r, c);
        if (r == 3) smem[136 + nxt * 64 + e] = h;
      }
      __syncthreads();
    }
  }
}

extern "C" void kernel_launch(void* const* d_in, const int* in_sizes, int n_in,
                              void* d_out, int out_size, void* d_ws, size_t ws_size,
                              hipStream_t stream) {
  const float* y    = (const float*)d_in[0];
  const float* Wih0 = (const float*)d_in[1];
  const float* Whh0 = (const float*)d_in[2];
  const float* bih0 = (const float*)d_in[3];
  const float* bhh0 = (const float*)d_in[4];
  const float* Wih1 = (const float*)d_in[5];
  const float* Whh1 = (const float*)d_in[6];
  const float* bih1 = (const float*)d_in[7];
  const float* bhh1 = (const float*)d_in[8];
  const float* Wlin = (const float*)d_in[9];
  const float* blin = (const float*)d_in[10];

  rnn_fused<<<dim3(1), dim3(512), 0, stream>>>(
      y, Wih0, Whh0, bih0, bhh0, Wih1, Whh1, bih1, bhh1, Wlin, blin,
      (float*)d_out);
}